// Round 1
// baseline (369.726 us; speedup 1.0000x reference)
//
#include <hip/hip_runtime.h>

// SeriesDecomp: trend = mean of moving averages (k = 7, 25, 49, replicate pad),
// residual = x - trend.  x: [32, 4096, 512] fp32.
// d_out = [residual (B*L*C floats) | trend (B*L*C floats)].
//
// Strategy: memory-bound -> one pass, running window sums per thread.
// Thread owns one float4 channel-group (c4) of one batch, walks a 64-step
// time chunk. Lane i reads channels 4i..4i+3 -> coalesced float4 loads.
// Window updates re-read +/- halo values; those hit L1 (sequential walk).

namespace {
constexpr int B = 32;
constexpr int L = 4096;
constexpr int C = 512;
constexpr int C4 = C / 4;      // 128 float4 channel-groups
constexpr int CHUNK = 64;      // time steps per block

__device__ __forceinline__ float4 f4add(float4 a, float4 b) {
    return make_float4(a.x + b.x, a.y + b.y, a.z + b.z, a.w + b.w);
}
__device__ __forceinline__ float4 f4sub(float4 a, float4 b) {
    return make_float4(a.x - b.x, a.y - b.y, a.z - b.z, a.w - b.w);
}

template <bool CLAMP>
__device__ __forceinline__ void decomp_body(const float4* __restrict__ p,
                                            float4* __restrict__ rp,
                                            float4* __restrict__ tp,
                                            int t0) {
    const float inv7 = 1.0f / 7.0f, inv25 = 1.0f / 25.0f, inv49 = 1.0f / 49.0f;
    const float inv3 = 1.0f / 3.0f;

    auto ld = [&](int j) -> float4 {
        if (CLAMP) j = min(max(j, 0), L - 1);
        return p[(size_t)j * C4];
    };

    float4 s7  = make_float4(0.f, 0.f, 0.f, 0.f);
    float4 s25 = s7;
    float4 s49 = s7;

    // Initialize the three window sums centered at t0 (single pass, widths 49/25/7).
#pragma unroll
    for (int d = -24; d <= 24; ++d) {
        float4 v = ld(t0 + d);
        s49 = f4add(s49, v);
        if (d >= -12 && d <= 12) s25 = f4add(s25, v);
        if (d >= -3 && d <= 3)   s7  = f4add(s7, v);
    }

    for (int t = t0; t < t0 + CHUNK; ++t) {
        float4 xv = p[(size_t)t * C4];  // t always in [0, L), no clamp needed
        float4 tr;
        tr.x = (s7.x * inv7 + s25.x * inv25 + s49.x * inv49) * inv3;
        tr.y = (s7.y * inv7 + s25.y * inv25 + s49.y * inv49) * inv3;
        tr.z = (s7.z * inv7 + s25.z * inv25 + s49.z * inv49) * inv3;
        tr.w = (s7.w * inv7 + s25.w * inv25 + s49.w * inv49) * inv3;

        tp[(size_t)t * C4] = tr;
        rp[(size_t)t * C4] = f4sub(xv, tr);

        // Slide all three windows one step: add incoming, drop outgoing.
        s7  = f4add(s7,  f4sub(ld(t + 4),  ld(t - 3)));
        s25 = f4add(s25, f4sub(ld(t + 13), ld(t - 12)));
        s49 = f4add(s49, f4sub(ld(t + 25), ld(t - 24)));
    }
}

__global__ __launch_bounds__(C4) void series_decomp_kernel(
    const float4* __restrict__ x,
    float4* __restrict__ res,
    float4* __restrict__ trend) {
    const int c4 = threadIdx.x;          // 0..127
    const int chunk = blockIdx.x;        // 0..L/CHUNK-1
    const int b = blockIdx.y;            // 0..B-1
    const int t0 = chunk * CHUNK;

    const size_t base = ((size_t)b * L) * C4 + c4;
    const float4* p = x + base;
    float4* rp = res + base;
    float4* tp = trend + base;

    // Interior chunks never touch indices outside [0, L): clamp-free fast path.
    if (t0 - 24 >= 0 && t0 + CHUNK - 1 + 25 <= L - 1) {
        decomp_body<false>(p, rp, tp, t0);
    } else {
        decomp_body<true>(p, rp, tp, t0);
    }
}

}  // namespace

extern "C" void kernel_launch(void* const* d_in, const int* in_sizes, int n_in,
                              void* d_out, int out_size, void* d_ws, size_t ws_size,
                              hipStream_t stream) {
    (void)in_sizes; (void)n_in; (void)out_size; (void)d_ws; (void)ws_size;

    const float4* x = (const float4*)d_in[0];
    float4* res = (float4*)d_out;                       // residual first
    float4* trend = res + (size_t)B * L * C4;           // then trend

    dim3 grid(L / CHUNK, B);
    series_decomp_kernel<<<grid, C4, 0, stream>>>(x, res, trend);
}

// Round 2
// 334.666 us; speedup vs baseline: 1.1048x; 1.1048x over previous
//
#include <hip/hip_runtime.h>

// SeriesDecomp: trend = mean of moving averages (k = 7, 25, 49, replicate pad),
// residual = x - trend.  x: [32, 4096, 512] fp32.
// d_out = [residual | trend], each B*L*C floats.
//
// R2 strategy: R1 showed 3.7x HBM read amplification (983 MB fetched vs 268 MB
// input) because the 6 halo re-reads per step thrash L1/L2. Fix: per-thread
// 50-deep register ring buffer holding x[t-24..t+25]; every element is loaded
// from HBM exactly once per block. Time loop fully unrolled so all ring
// indices are compile-time constants (runtime-indexed arrays would spill to
// scratch, rule #20).

namespace {
constexpr int B = 32;
constexpr int L = 4096;
constexpr int C = 512;
constexpr int C2 = C / 2;      // 256 float2 channel-pairs per row
constexpr int CHUNK = 128;     // time steps per block (fully unrolled)
constexpr int RING = 50;       // window span: x[t-24 .. t+25]

template <bool CLAMP>
__device__ __forceinline__ void decomp_body(const float2* __restrict__ p,
                                            float2* __restrict__ rp,
                                            float2* __restrict__ tp,
                                            int t0) {
    float2 ring[RING];

    auto ld = [&](int j) -> float2 {
        if (CLAMP) j = min(max(j, 0), L - 1);
        return p[(size_t)j * C2];
    };

    // Prologue: fill slots 0..48 with x[t0-24 .. t0+24]; build window sums
    // centered at t0.  slot(j) = (j + 24 - t0) mod RING.
    float sx7 = 0.f, sy7 = 0.f, sx25 = 0.f, sy25 = 0.f, sx49 = 0.f, sy49 = 0.f;
#pragma unroll
    for (int k = 0; k < RING - 1; ++k) {
        float2 v = ld(t0 - 24 + k);
        ring[k] = v;
        sx49 += v.x; sy49 += v.y;
        if (k >= 12 && k <= 36) { sx25 += v.x; sy25 += v.y; }
        if (k >= 21 && k <= 27) { sx7  += v.x; sy7  += v.y; }
    }

    const float inv7 = 1.f / 7.f, inv25 = 1.f / 25.f, inv49 = 1.f / 49.f;
    const float inv3 = 1.f / 3.f;

#pragma unroll
    for (int i = 0; i < CHUNK; ++i) {
        const int t = t0 + i;
        // Fresh front value x[t+25] -> slot (i+49)%RING (held x[t-25], dead).
        ring[(i + RING - 1) % RING] = ld(t + 25);

        float2 xv = ring[(i + 24) % RING];              // x[t]
        float tx = (sx7 * inv7 + sx25 * inv25 + sx49 * inv49) * inv3;
        float ty = (sy7 * inv7 + sy25 * inv25 + sy49 * inv49) * inv3;

        tp[(size_t)t * C2] = make_float2(tx, ty);
        rp[(size_t)t * C2] = make_float2(xv.x - tx, xv.y - ty);

        // Slide windows to center t+1 (all indices compile-time constants).
        float2 a7  = ring[(i + 28) % RING];             // x[t+4]
        float2 d7  = ring[(i + 21) % RING];             // x[t-3]
        float2 a25 = ring[(i + 37) % RING];             // x[t+13]
        float2 d25 = ring[(i + 12) % RING];             // x[t-12]
        float2 a49 = ring[(i + RING - 1) % RING];       // x[t+25]
        float2 d49 = ring[i % RING];                    // x[t-24]
        sx7  += a7.x  - d7.x;   sy7  += a7.y  - d7.y;
        sx25 += a25.x - d25.x;  sy25 += a25.y - d25.y;
        sx49 += a49.x - d49.x;  sy49 += a49.y - d49.y;
    }
}

__global__ __launch_bounds__(256, 4) void series_decomp_kernel(
    const float2* __restrict__ x,
    float2* __restrict__ res,
    float2* __restrict__ trend) {
    const int c2 = threadIdx.x;          // 0..255 channel-pair
    const int chunk = blockIdx.x;        // 0..L/CHUNK-1
    const int b = blockIdx.y;            // 0..B-1
    const int t0 = chunk * CHUNK;

    const size_t base = ((size_t)b * L) * C2 + c2;
    const float2* p = x + base;
    float2* rp = res + base;
    float2* tp = trend + base;

    // Interior chunks never index outside [0, L): clamp-free fast path.
    if (t0 - 24 >= 0 && t0 + CHUNK - 1 + 25 <= L - 1) {
        decomp_body<false>(p, rp, tp, t0);
    } else {
        decomp_body<true>(p, rp, tp, t0);
    }
}

}  // namespace

extern "C" void kernel_launch(void* const* d_in, const int* in_sizes, int n_in,
                              void* d_out, int out_size, void* d_ws, size_t ws_size,
                              hipStream_t stream) {
    (void)in_sizes; (void)n_in; (void)out_size; (void)d_ws; (void)ws_size;

    const float2* x = (const float2*)d_in[0];
    float2* res = (float2*)d_out;                       // residual first
    float2* trend = res + (size_t)B * L * C2;           // then trend

    dim3 grid(L / CHUNK, B);
    series_decomp_kernel<<<grid, 256, 0, stream>>>(x, res, trend);
}

// Round 3
// 173.094 us; speedup vs baseline: 2.1360x; 1.9334x over previous
//
#include <hip/hip_runtime.h>

// SeriesDecomp: trend = mean of moving averages (k = 7, 25, 49, replicate pad),
// residual = x - trend.  x: [32, 4096, 512] fp32.
// d_out = [residual | trend], each B*L*C floats.
//
// R3: R2's register ring spilled to scratch (VGPR=64 < 100 needed; WRITE_SIZE
// +337 MB of spill traffic). Replace with an LDS delay line staged by
// global_load_lds (width 4: LDS dest = wave-uniform base + lane*4 matches the
// ring[slot][256ch] layout exactly; bank = tid%32 -> conflict-free).
// Counted-vmcnt prefetch 2 groups (16 rows) ahead, never draining to 0 in
// steady state (T4). No barriers: each wave stages/reads only its own 64
// channels. Running window sums live in 6 scalar registers.

namespace {
constexpr int B = 32;
constexpr int L = 4096;
constexpr int C = 512;
constexpr int CPB = 256;      // channels per block (2 channel-groups over C=512)
constexpr int CHUNK = 256;    // time steps per block
constexpr int G = 8;          // steps per group
constexpr int NG = CHUNK / G; // 32 groups
constexpr int RING = 80;      // ring rows; 80*256*4B = 80 KB -> 2 blocks/CU.
                              // live footprint = 57 read-span + 16 in-flight = 73 <= 80.

// Inline-asm counted wait + sched fence (rule #18). "memory" clobber pins all
// VMEM ops (stage issues + output stores) between consecutive WAITVs, so the
// per-window vmcnt FIFO counts below are exact regardless of scheduling.
#define WAITV(N)                                                     \
  do {                                                               \
    asm volatile("s_waitcnt vmcnt(" #N ")" ::: "memory");            \
    __builtin_amdgcn_sched_barrier(0);                               \
  } while (0)

__global__ __launch_bounds__(256, 2) void series_decomp_kernel(
    const float* __restrict__ x,
    float* __restrict__ res,
    float* __restrict__ trend) {
  __shared__ float ring[RING * CPB];

  const int tid = threadIdx.x;     // channel within block, 0..255
  const int chunk = blockIdx.x;    // 0..15
  const int chg = blockIdx.y;      // 0..1
  const int b = blockIdx.z;        // 0..31
  const int t0 = chunk * CHUNK;
  const int ch = chg * CPB + tid;

  const size_t colbase = (size_t)b * L * C + ch;
  const float* xp = x + colbase;
  float* lds_wave = ring + (tid & ~63);  // wave-uniform base (+ slot*CPB per row)

  // Stage row r (replicate-clamped) into ring[slot(r)][wave's 64 channels].
  auto stage = [&](int r) {
    int rc = min(max(r, 0), L - 1);
    int slot = (r + RING) % RING;  // r >= -24, consistent with read-side slots
    const float* gp = xp + (size_t)rc * C;
    __builtin_amdgcn_global_load_lds(
        (const __attribute__((address_space(1))) void*)gp,
        (__attribute__((address_space(3))) void*)(lds_wave + slot * CPB),
        4, 0, 0);
  };

  // ---- Prologue: stage rows t0-24 .. t0+40 (65 loads) ----
  for (int r = t0 - 24; r <= t0 + 40; ++r) stage(r);
  WAITV(16);  // drain oldest 49 = rows t0-24..t0+24 (init span)

  // Initial window sums centered at t0.
  float s7v = 0.f, s25v = 0.f, s49v = 0.f;
#pragma unroll
  for (int k = 0; k < 49; ++k) {  // row = t0-24+k
    int sl = (t0 - 24 + k + RING) % RING;
    float v = ring[sl * CPB + tid];
    s49v += v;
    if (k >= 12 && k <= 36) s25v += v;  // rows t0-12..t0+12
    if (k >= 21 && k <= 27) s7v += v;   // rows t0-3..t0+3
  }

  const float inv7 = 1.f / 7.f, inv25 = 1.f / 25.f, inv49 = 1.f / 49.f;
  const float inv3 = 1.f / 3.f;

  int st = t0 % RING;  // slot of row t
  float* rp = res + colbase + (size_t)t0 * C;
  float* tp = trend + colbase + (size_t)t0 * C;
  int pf = t0 + 41;  // next row to prefetch (group g stages rows for group g+2)

  for (int g = 0; g < NG; ++g) {
    // Issue prefetch for group g+2 (8 rows; tail groups clamp past L, harmless).
#pragma unroll
    for (int j = 0; j < G; ++j) stage(pf + j);
    pf += G;

    // Drain need(g) = rows t0+8g+25..32. FIFO at this point (steady state):
    // need(g)[8] stores[16] need(g+1)[8] stores[16] need(g+2)[8] = 56 -> 48.
    if (g == 0) {
      WAITV(16);      // queue: rows +25..+40 (16) + new (8) = 24 -> drain rows +25..+32
    } else if (g == 1) {
      WAITV(32);      // queue: +33..40(8) stage(8) stores(16) stage(8) = 40 -> drain +33..40
    } else {
      WAITV(48);
    }

#pragma unroll
    for (int j = 0; j < G; ++j) {
      // Taps: slot(t+d) = (st + (d mod RING)) mod RING, one wrap-subtract each.
      float xv = ring[st * CPB + tid];
      int s1 = st + 4;  if (s1 >= RING) s1 -= RING;  float a7  = ring[s1 * CPB + tid];
      int s2 = st + 77; if (s2 >= RING) s2 -= RING;  float d7  = ring[s2 * CPB + tid];
      int s3 = st + 13; if (s3 >= RING) s3 -= RING;  float a25 = ring[s3 * CPB + tid];
      int s4 = st + 68; if (s4 >= RING) s4 -= RING;  float d25 = ring[s4 * CPB + tid];
      int s5 = st + 25; if (s5 >= RING) s5 -= RING;  float a49 = ring[s5 * CPB + tid];
      int s6 = st + 56; if (s6 >= RING) s6 -= RING;  float d49 = ring[s6 * CPB + tid];

      float tr = (s7v * inv7 + s25v * inv25 + s49v * inv49) * inv3;
      *tp = tr;
      *rp = xv - tr;
      tp += C;
      rp += C;

      // Slide windows to center t+1.
      s7v  += a7  - d7;
      s25v += a25 - d25;
      s49v += a49 - d49;
      ++st; if (st >= RING) st = 0;
    }
  }
}

}  // namespace

extern "C" void kernel_launch(void* const* d_in, const int* in_sizes, int n_in,
                              void* d_out, int out_size, void* d_ws, size_t ws_size,
                              hipStream_t stream) {
  (void)in_sizes; (void)n_in; (void)out_size; (void)d_ws; (void)ws_size;

  const float* x = (const float*)d_in[0];
  float* res = (float*)d_out;                        // residual first
  float* trend = res + (size_t)B * L * C;            // then trend

  dim3 grid(L / CHUNK, C / CPB, B);                  // (16, 2, 32) = 1024 blocks
  series_decomp_kernel<<<grid, CPB, 0, stream>>>(x, res, trend);
}

// Round 4
// 159.305 us; speedup vs baseline: 2.3209x; 1.0866x over previous
//
#include <hip/hip_runtime.h>

// SeriesDecomp: trend = mean of moving averages (k = 7, 25, 49, replicate pad),
// residual = x - trend.  x: [32, 4096, 512] fp32.
// d_out = [residual | trend], each B*L*C floats.
//
// R4: pure register delay line. 64-slot FIFO, 64-step fully-unrolled body ->
// every index is a compile-time constant ((i+c)&63), so SROA keeps the FIFO
// in VGPRs (R2's spill came from a declined 128-step unroll w/ %50 indices).
// Slot of row r is r&63 (t0 multiple of 512 -> phase 0). Load issued at step
// i targets the slot freed at step i-1 and is consumed 14 steps later ->
// structural prefetch; compiler-inserted counted vmcnt covers the latency.
// No LDS, no barriers, no inline asm. 7 taps/step come from registers.

namespace {
constexpr int B = 32;
constexpr int L = 4096;
constexpr int C = 512;
constexpr int CPB = 256;          // channels per block
constexpr int CHUNK = 512;        // time steps per block
constexpr int BODY = 64;          // unrolled steps == FIFO depth
constexpr int NB = CHUNK / BODY;  // 8 outer iterations
constexpr int PF = 14;            // prefetch beyond t+25; span 50+14 = 64 exact

__global__ __launch_bounds__(256, 2) void series_decomp_kernel(
    const float* __restrict__ x,
    float* __restrict__ res,
    float* __restrict__ trend) {
  const int tid = threadIdx.x;     // channel within block, 0..255
  const int chunk = blockIdx.x;    // 0..7
  const int chg = blockIdx.y;      // 0..1
  const int b = blockIdx.z;        // 0..31
  const int t0 = chunk * CHUNK;    // multiple of 512 -> t0 & 63 == 0
  const int ch = chg * CPB + tid;

  const size_t colbase = (size_t)b * L * C + ch;
  const float* xp = x + colbase;

  float fifo[BODY];  // slot (r & 63) holds x[r] for a sliding 64-row span

  // Prologue: rows t0-24 .. t0+38 -> slots (k+40)&63, k = 0..62.
  // Slot 39 is first written by step i=0 of the main body.
#pragma unroll
  for (int k = 0; k < BODY - 1; ++k) {
    int r = t0 - 24 + k;
    r = min(max(r, 0), L - 1);     // replicate pad (low edge only matters here)
    fifo[(k + 40) & 63] = xp[(size_t)r * C];
  }

  // Initial window sums centered at t0 (rows t0-24 .. t0+24 = k 0..48).
  float s7 = 0.f, s25 = 0.f, s49 = 0.f;
#pragma unroll
  for (int k = 0; k < 49; ++k) {
    float v = fifo[(k + 40) & 63];
    s49 += v;
    if (k >= 12 && k <= 36) s25 += v;   // rows t0-12..t0+12
    if (k >= 21 && k <= 27) s7  += v;   // rows t0-3..t0+3
  }

  // Folded coefficients: trend = s7/(7*3) + s25/(25*3) + s49/(49*3).
  const float c7 = 1.f / 21.f, c25 = 1.f / 75.f, c49 = 1.f / 147.f;

  float* rp = res + colbase + (size_t)t0 * C;
  float* tp = trend + colbase + (size_t)t0 * C;

  for (int g = 0; g < NB; ++g) {
    const int tb = t0 + g * BODY;  // tb & 63 == 0 -> slot(row r) = r & 63
#pragma unroll
    for (int i = 0; i < BODY; ++i) {
      // Prefetch row tb+i+39 into slot (i+39)&63. Its old content (row
      // tb+i-25) was last read as d49 at step i-1 -> WAR-safe, and the new
      // value is first read as a49 at step i+14 -> 14-step latency cover.
      {
        int r = min(tb + i + 25 + PF, L - 1);   // r >= 39 > 0 always
        fifo[(i + 25 + PF) & 63] = xp[(size_t)r * C];
      }

      float xv  = fifo[i & 63];          // x[t]
      float a7  = fifo[(i + 4)  & 63];   // x[t+4]
      float d7  = fifo[(i + 61) & 63];   // x[t-3]
      float a25 = fifo[(i + 13) & 63];   // x[t+13]
      float d25 = fifo[(i + 52) & 63];   // x[t-12]
      float a49 = fifo[(i + 25) & 63];   // x[t+25]
      float d49 = fifo[(i + 40) & 63];   // x[t-24]

      float tr = s7 * c7 + s25 * c25 + s49 * c49;
      *tp = tr;
      *rp = xv - tr;
      tp += C;
      rp += C;

      // Slide all three windows to center t+1.
      s7  += a7  - d7;
      s25 += a25 - d25;
      s49 += a49 - d49;
    }
  }
}

}  // namespace

extern "C" void kernel_launch(void* const* d_in, const int* in_sizes, int n_in,
                              void* d_out, int out_size, void* d_ws, size_t ws_size,
                              hipStream_t stream) {
  (void)in_sizes; (void)n_in; (void)out_size; (void)d_ws; (void)ws_size;

  const float* x = (const float*)d_in[0];
  float* res = (float*)d_out;                        // residual first
  float* trend = res + (size_t)B * L * C;            // then trend

  dim3 grid(L / CHUNK, C / CPB, B);                  // (8, 2, 32) = 512 blocks
  series_decomp_kernel<<<grid, CPB, 0, stream>>>(x, res, trend);
}